// Round 1
// baseline (131.216 us; speedup 1.0000x reference)
//
#include <hip/hip_runtime.h>
#include <hip/hip_bf16.h>

// Shapes: B=4, H=8, N=128, L=128, D=64
// attn = softmax(mask ? QK^T/8 : -32768) @ V, per (b,h,n) head.
// One block per head (4096 blocks), 256 threads = 4 waves, wave owns 32 q-rows.

typedef __bf16 bf16;
typedef bf16 bf16x4 __attribute__((ext_vector_type(4)));
typedef bf16 bf16x8 __attribute__((ext_vector_type(8)));
typedef float f32x4 __attribute__((ext_vector_type(4)));

#define MFMA16(a, b, c) __builtin_amdgcn_mfma_f32_16x16x32_bf16((a), (b), (c), 0, 0, 0)

__global__ __launch_bounds__(256, 2) void attn_head_kernel(
    const float* __restrict__ q, const float* __restrict__ k,
    const float* __restrict__ v, const int* __restrict__ mask,
    float* __restrict__ out)
{
    constexpr int H = 8, N = 128, L = 128, D = 64;

    // LDS: K row-major (padded), V transposed (padded), per-wave P chunk.
    __shared__ bf16 KL[128][72];    // 18432 B, row stride 144 B (16B-mult)
    __shared__ bf16 VT[64][136];    // 17408 B, row stride 272 B (16B-mult)
    __shared__ bf16 PL[4][32][40];  // 10240 B, row stride 80 B  (16B-mult)

    // XCD-aware swizzle: nwg=4096 divisible by 8. Heads (h fastest) of the
    // same (b,n) land in the same per-XCD chunk -> mask tile hits L2.
    int bid = blockIdx.x;
    int l   = (bid & 7) * 512 + (bid >> 3);
    int h   = l & 7;
    int n   = (l >> 3) & 127;
    int b   = l >> 10;

    const size_t base = (((size_t)(b * H + h)) * N + n) * (size_t)(L * D);
    const float* Qp = q + base;
    const float* Kp = k + base;
    const float* Vp = v + base;
    float*       Op = out + base;
    const int*   Mp = mask + ((size_t)(b * N + n)) * (size_t)(L * L);

    const int tid  = threadIdx.x;
    const int wave = tid >> 6;
    const int lane = tid & 63;
    const int g    = lane >> 4;   // 16-lane group (k-group of MFMA frags)
    const int c    = lane & 15;   // row/col index within fragment

    // ---- Stage K -> KL (bf16), V -> VT (bf16, transposed) ----
    #pragma unroll
    for (int i = 0; i < 8; ++i) {
        int e   = i * 256 + tid;      // float4 index, 16 per row
        int row = e >> 4;
        int d0  = (e & 15) * 4;
        float4 kv = ((const float4*)Kp)[e];
        bf16x4 pk = { (bf16)kv.x, (bf16)kv.y, (bf16)kv.z, (bf16)kv.w };
        *(bf16x4*)&KL[row][d0] = pk;
        float4 vv = ((const float4*)Vp)[e];
        VT[d0 + 0][row] = (bf16)vv.x;
        VT[d0 + 1][row] = (bf16)vv.y;
        VT[d0 + 2][row] = (bf16)vv.z;
        VT[d0 + 3][row] = (bf16)vv.w;
    }

    // ---- Q A-fragments straight from global (wave-private rows) ----
    bf16x8 qa[2][2];  // [row-tile][k-step]
    #pragma unroll
    for (int rt = 0; rt < 2; ++rt)
        #pragma unroll
        for (int ds = 0; ds < 2; ++ds) {
            int row = wave * 32 + rt * 16 + c;
            int d0  = ds * 32 + g * 8;
            const float4* p = (const float4*)(Qp + row * D + d0);
            float4 x0 = p[0], x1 = p[1];
            bf16x8 f = { (bf16)x0.x, (bf16)x0.y, (bf16)x0.z, (bf16)x0.w,
                         (bf16)x1.x, (bf16)x1.y, (bf16)x1.z, (bf16)x1.w };
            qa[rt][ds] = f;
        }

    __syncthreads();

    // ---- S = Q K^T  (2 row-tiles x 8 col-tiles of 16x16) ----
    f32x4 acc[2][8];
    #pragma unroll
    for (int rt = 0; rt < 2; ++rt)
        #pragma unroll
        for (int ct = 0; ct < 8; ++ct)
            acc[rt][ct] = (f32x4){0.f, 0.f, 0.f, 0.f};

    #pragma unroll
    for (int ct = 0; ct < 8; ++ct) {
        bf16x8 kb0 = *(const bf16x8*)&KL[ct * 16 + c][g * 8];
        bf16x8 kb1 = *(const bf16x8*)&KL[ct * 16 + c][32 + g * 8];
        #pragma unroll
        for (int rt = 0; rt < 2; ++rt) {
            acc[rt][ct] = MFMA16(qa[rt][0], kb0, acc[rt][ct]);
            acc[rt][ct] = MFMA16(qa[rt][1], kb1, acc[rt][ct]);
        }
    }

    // ---- masked softmax (rows: wave*32 + rt*16 + g*4 + j) ----
    // Leaves unnormalized exp() in acc; rinv holds 1/rowsum for the epilogue.
    float rinv[2][4];
    #pragma unroll
    for (int rt = 0; rt < 2; ++rt)
        #pragma unroll
        for (int j = 0; j < 4; ++j) {
            int row = wave * 32 + rt * 16 + g * 4 + j;
            const int* mrow = Mp + row * L;
            float vv[8];
            float mx = -3.4e38f;
            #pragma unroll
            for (int ct = 0; ct < 8; ++ct) {
                float s = acc[rt][ct][j] * 0.125f;   // / TEMPERATURE
                int m = mrow[ct * 16 + c];
                s = (m == 0) ? -32768.0f : s;        // NEG fill
                vv[ct] = s;
                mx = fmaxf(mx, s);
            }
            mx = fmaxf(mx, __shfl_xor(mx, 1));
            mx = fmaxf(mx, __shfl_xor(mx, 2));
            mx = fmaxf(mx, __shfl_xor(mx, 4));
            mx = fmaxf(mx, __shfl_xor(mx, 8));
            float sum = 0.f;
            #pragma unroll
            for (int ct = 0; ct < 8; ++ct) {
                float e = __expf(vv[ct] - mx);       // masked -> exp(<<0) = 0
                acc[rt][ct][j] = e;
                sum += e;
            }
            sum += __shfl_xor(sum, 1);
            sum += __shfl_xor(sum, 2);
            sum += __shfl_xor(sum, 4);
            sum += __shfl_xor(sum, 8);
            rinv[rt][j] = __builtin_amdgcn_rcpf(sum);
        }

    // ---- O = P V  (k in 4 chunks of 32; P relayout via per-wave LDS) ----
    f32x4 oacc[2][4];
    #pragma unroll
    for (int rt = 0; rt < 2; ++rt)
        #pragma unroll
        for (int dt = 0; dt < 4; ++dt)
            oacc[rt][dt] = (f32x4){0.f, 0.f, 0.f, 0.f};

    for (int kc = 0; kc < 4; ++kc) {
        #pragma unroll
        for (int rt = 0; rt < 2; ++rt)
            #pragma unroll
            for (int cc = 0; cc < 2; ++cc) {
                int ct = kc * 2 + cc;
                #pragma unroll
                for (int j = 0; j < 4; ++j)
                    PL[wave][rt * 16 + g * 4 + j][cc * 16 + c] = (bf16)acc[rt][ct][j];
            }
        __syncthreads();  // uniform; orders per-wave PL write->read cheaply

        bf16x8 vb[4];
        #pragma unroll
        for (int dt = 0; dt < 4; ++dt)
            vb[dt] = *(const bf16x8*)&VT[dt * 16 + c][kc * 32 + g * 8];
        #pragma unroll
        for (int rt = 0; rt < 2; ++rt) {
            bf16x8 pa = *(const bf16x8*)&PL[wave][rt * 16 + c][g * 8];
            #pragma unroll
            for (int dt = 0; dt < 4; ++dt)
                oacc[rt][dt] = MFMA16(pa, vb[dt], oacc[rt][dt]);
        }
        __syncthreads();  // protect PL against next-iteration overwrite
    }

    // ---- normalize + store (f32 out) ----
    #pragma unroll
    for (int rt = 0; rt < 2; ++rt)
        #pragma unroll
        for (int j = 0; j < 4; ++j) {
            int row = wave * 32 + rt * 16 + g * 4 + j;
            float invs = rinv[rt][j];
            float* orow = Op + row * D;
            #pragma unroll
            for (int dt = 0; dt < 4; ++dt)
                orow[dt * 16 + c] = oacc[rt][dt][j] * invs;
        }
}

extern "C" void kernel_launch(void* const* d_in, const int* in_sizes, int n_in,
                              void* d_out, int out_size, void* d_ws, size_t ws_size,
                              hipStream_t stream) {
    const float* q    = (const float*)d_in[0];
    const float* k    = (const float*)d_in[1];
    const float* v    = (const float*)d_in[2];
    const int*   mask = (const int*)d_in[3];
    float*       out  = (float*)d_out;
    attn_head_kernel<<<4096, 256, 0, stream>>>(q, k, v, mask, out);
}

// Round 2
// 118.196 us; speedup vs baseline: 1.1102x; 1.1102x over previous
//
#include <hip/hip_runtime.h>
#include <hip/hip_bf16.h>

// B=4,H=8,N=128,L=128,D=64.  out = softmax(mask? QK^T/8 : -2^15) @ V per head.
// One block per head, 256 threads = 4 waves, wave owns 32 q-rows.
// Swapped-operand design: S^T = mfma(K, Q^T) so each lane's scores live on one
// q-row (q = lane&15) -> int4 mask loads, 2-shfl softmax, in-lane normalize,
// packed P writes. P buffer overlays dead K region; PV needs no block barrier.

typedef __bf16 bf16;
typedef bf16 bf16x4 __attribute__((ext_vector_type(4)));
typedef bf16 bf16x8 __attribute__((ext_vector_type(8)));
typedef float f32x4 __attribute__((ext_vector_type(4)));

#define MFMA16(a, b, c) __builtin_amdgcn_mfma_f32_16x16x32_bf16((a), (b), (c), 0, 0, 0)

__global__ __launch_bounds__(256, 4) void attn_head_kernel(
    const float* __restrict__ q, const float* __restrict__ k,
    const float* __restrict__ v, const int* __restrict__ mask,
    float* __restrict__ out)
{
    constexpr int H = 8, N = 128, L = 128, D = 64;

    // 35840 B total -> 4 blocks/CU.
    __shared__ __align__(16) char SMEM[35840];
    bf16 (*KL)[72]  = (bf16(*)[72])SMEM;             // K row-major, 18432 B (dead after QK)
    bf16 (*VT)[136] = (bf16(*)[136])(SMEM + 18432);  // V^T, 17408 B

    // XCD-aware swizzle (4096 % 8 == 0): heads of one (b,n) share an XCD's L2
    // so the mask tile is fetched from HBM once.
    int bid  = blockIdx.x;
    int lidx = (bid & 7) * 512 + (bid >> 3);
    int h = lidx & 7, n = (lidx >> 3) & 127, b = lidx >> 10;

    const size_t base = (((size_t)(b * H + h)) * N + n) * (size_t)(L * D);
    const float* Qp = q + base;
    const float* Kp = k + base;
    const float* Vp = v + base;
    float*       Op = out + base;
    const int*   Mp = mask + ((size_t)(b * N + n)) * (size_t)(L * L);

    const int tid  = threadIdx.x;
    const int wave = tid >> 6;
    const int lane = tid & 63;
    const int g    = lane >> 4;   // k-group of the MFMA fragment
    const int c    = lane & 15;

    // ---- stage K -> KL (bf16, row-major, packed b64 writes) ----
    #pragma unroll
    for (int i = 0; i < 8; ++i) {
        int e   = i * 256 + tid;
        int row = e >> 4;
        int d0  = (e & 15) * 4;
        float4 kv = ((const float4*)Kp)[e];
        bf16x4 pk = { (bf16)kv.x, (bf16)kv.y, (bf16)kv.z, (bf16)kv.w };
        *(bf16x4*)&KL[row][d0] = pk;
    }
    // ---- stage V -> VT via register 4x4 transpose (packed b64 writes) ----
    #pragma unroll
    for (int i = 0; i < 2; ++i) {
        int id = i * 256 + tid;
        int db = id & 15;          // d-block (0..15)
        int kb = id >> 4;          // k-block (0..31)
        const float4* vp = (const float4*)(Vp + kb * 4 * 64 + db * 4);
        float4 r0 = vp[0], r1 = vp[16], r2 = vp[32], r3 = vp[48];
        bf16x4 w0 = { (bf16)r0.x, (bf16)r1.x, (bf16)r2.x, (bf16)r3.x };
        bf16x4 w1 = { (bf16)r0.y, (bf16)r1.y, (bf16)r2.y, (bf16)r3.y };
        bf16x4 w2 = { (bf16)r0.z, (bf16)r1.z, (bf16)r2.z, (bf16)r3.z };
        bf16x4 w3 = { (bf16)r0.w, (bf16)r1.w, (bf16)r2.w, (bf16)r3.w };
        *(bf16x4*)&VT[db * 4 + 0][kb * 4] = w0;
        *(bf16x4*)&VT[db * 4 + 1][kb * 4] = w1;
        *(bf16x4*)&VT[db * 4 + 2][kb * 4] = w2;
        *(bf16x4*)&VT[db * 4 + 3][kb * 4] = w3;
    }

    // ---- Q B-fragments from global, pre-scaled by 1/TEMPERATURE (exact in bf16) ----
    bf16x8 qb[2][2];  // [row-tile][k(=d)-step]
    #pragma unroll
    for (int rt = 0; rt < 2; ++rt)
        #pragma unroll
        for (int ds = 0; ds < 2; ++ds) {
            int row = wave * 32 + rt * 16 + c;
            const float4* p = (const float4*)(Qp + row * D + ds * 32 + g * 8);
            float4 x0 = p[0], x1 = p[1];
            bf16x8 f = { (bf16)(x0.x * 0.125f), (bf16)(x0.y * 0.125f),
                         (bf16)(x0.z * 0.125f), (bf16)(x0.w * 0.125f),
                         (bf16)(x1.x * 0.125f), (bf16)(x1.y * 0.125f),
                         (bf16)(x1.z * 0.125f), (bf16)(x1.w * 0.125f) };
            qb[rt][ds] = f;
        }

    __syncthreads();

    // ---- S^T = K Q^T : acc[kt][rt], row(g*4+j)=k, col(c)=q ----
    f32x4 acc[8][2];
    #pragma unroll
    for (int kt = 0; kt < 8; ++kt)
        #pragma unroll
        for (int rt = 0; rt < 2; ++rt)
            acc[kt][rt] = (f32x4){0.f, 0.f, 0.f, 0.f};

    #pragma unroll
    for (int kt = 0; kt < 8; ++kt) {
        bf16x8 ka0 = *(const bf16x8*)&KL[kt * 16 + c][g * 8];
        bf16x8 ka1 = *(const bf16x8*)&KL[kt * 16 + c][32 + g * 8];
        #pragma unroll
        for (int rt = 0; rt < 2; ++rt) {
            acc[kt][rt] = MFMA16(ka0, qb[rt][0], acc[kt][rt]);
            acc[kt][rt] = MFMA16(ka1, qb[rt][1], acc[kt][rt]);
        }
    }

    __syncthreads();  // all waves done reading KL before PL overlays it

    // ---- masked softmax; each lane owns q = wave*32 + rt*16 + c ----
    float rinv[2];
    #pragma unroll
    for (int rt = 0; rt < 2; ++rt) {
        int qrow = wave * 32 + rt * 16 + c;
        const int* mrow = Mp + (size_t)qrow * L;
        int4 mm[8];
        #pragma unroll
        for (int kt = 0; kt < 8; ++kt)
            mm[kt] = *(const int4*)(mrow + kt * 16 + g * 4);
        float mx = -3.0e38f;
        #pragma unroll
        for (int kt = 0; kt < 8; ++kt) {
            float s0 = mm[kt].x ? acc[kt][rt][0] : -32768.f;
            float s1 = mm[kt].y ? acc[kt][rt][1] : -32768.f;
            float s2 = mm[kt].z ? acc[kt][rt][2] : -32768.f;
            float s3 = mm[kt].w ? acc[kt][rt][3] : -32768.f;
            acc[kt][rt][0] = s0; acc[kt][rt][1] = s1;
            acc[kt][rt][2] = s2; acc[kt][rt][3] = s3;
            mx = fmaxf(mx, fmaxf(fmaxf(s0, s1), fmaxf(s2, s3)));
        }
        mx = fmaxf(mx, __shfl_xor(mx, 16));
        mx = fmaxf(mx, __shfl_xor(mx, 32));
        float sum = 0.f;
        #pragma unroll
        for (int kt = 0; kt < 8; ++kt) {
            #pragma unroll
            for (int j = 0; j < 4; ++j) {
                float e = __expf(acc[kt][rt][j] - mx);
                acc[kt][rt][j] = e;
                sum += e;
            }
        }
        sum += __shfl_xor(sum, 16);
        sum += __shfl_xor(sum, 32);
        rinv[rt] = __builtin_amdgcn_rcpf(sum);
    }

    // ---- O = P V, two k-half passes through per-wave PL (overlaid on KL) ----
    bf16* PLw = (bf16*)(SMEM + wave * 4608);  // [32][72] bf16 per wave
    f32x4 oacc[2][4];
    #pragma unroll
    for (int rt = 0; rt < 2; ++rt)
        #pragma unroll
        for (int dt = 0; dt < 4; ++dt)
            oacc[rt][dt] = (f32x4){0.f, 0.f, 0.f, 0.f};

    #pragma unroll
    for (int p = 0; p < 2; ++p) {
        // write normalized P (bf16) for k in [p*64, p*64+64): packed b64, k-contiguous
        #pragma unroll
        for (int rt = 0; rt < 2; ++rt) {
            float r = rinv[rt];
            #pragma unroll
            for (int t = 0; t < 4; ++t) {
                f32x4 a = acc[p * 4 + t][rt];
                bf16x4 w = { (bf16)(a[0] * r), (bf16)(a[1] * r),
                             (bf16)(a[2] * r), (bf16)(a[3] * r) };
                *(bf16x4*)&PLw[(rt * 16 + c) * 72 + t * 16 + g * 4] = w;
            }
        }
        // wave-local ordering: writes complete before reads issue (LDS in-order/wave)
        asm volatile("s_waitcnt lgkmcnt(0)" ::: "memory");
        __builtin_amdgcn_sched_barrier(0);

        #pragma unroll
        for (int kc2 = 0; kc2 < 2; ++kc2) {
            int kc = p * 2 + kc2;
            bf16x8 vb[4];
            #pragma unroll
            for (int dt = 0; dt < 4; ++dt)
                vb[dt] = *(const bf16x8*)&VT[dt * 16 + c][kc * 32 + g * 8];
            #pragma unroll
            for (int rt = 0; rt < 2; ++rt) {
                bf16x8 pa = *(const bf16x8*)&PLw[(rt * 16 + c) * 72 + kc2 * 32 + g * 8];
                #pragma unroll
                for (int dt = 0; dt < 4; ++dt)
                    oacc[rt][dt] = MFMA16(pa, vb[dt], oacc[rt][dt]);
            }
        }
        asm volatile("" ::: "memory");  // keep pass-1 writes after pass-0 reads
    }

    // ---- store (already normalized): O[q][d], row=g*4+j, col=c ----
    #pragma unroll
    for (int rt = 0; rt < 2; ++rt)
        #pragma unroll
        for (int j = 0; j < 4; ++j) {
            int row = wave * 32 + rt * 16 + g * 4 + j;
            float* orow = Op + row * D;
            #pragma unroll
            for (int dt = 0; dt < 4; ++dt)
                orow[dt * 16 + c] = oacc[rt][dt][j];
        }
}

extern "C" void kernel_launch(void* const* d_in, const int* in_sizes, int n_in,
                              void* d_out, int out_size, void* d_ws, size_t ws_size,
                              hipStream_t stream) {
    const float* q    = (const float*)d_in[0];
    const float* k    = (const float*)d_in[1];
    const float* v    = (const float*)d_in[2];
    const int*   mask = (const int*)d_in[3];
    float*       out  = (float*)d_out;
    attn_head_kernel<<<4096, 256, 0, stream>>>(q, k, v, mask, out);
}